// Round 1
// baseline (247.859 us; speedup 1.0000x reference)
//
#include <hip/hip_runtime.h>

#define HH 512
#define WW 512
#define NPART 11
#define NP 10            // parts actually used (drop last)
#define NB 16
#define NBP (NB * NP)    // 160 channels
#define CHUNKS 8
#define ROWS_PER_CHUNK (HH / CHUNKS)           // 64
#define BLOCK 256
#define F4_PER_CHUNK (ROWS_PER_CHUNK * WW / 4) // 8192 float4 per chunk
#define ITERS (F4_PER_CHUNK / BLOCK)           // 32

// Stage 1: per (channel, chunk) block computes 5 weighted partial sums.
// ws layout: ws[(bp*CHUNKS + chunk)*5 + {S,Sx,Sy,Sx2,Sy2}]
__global__ __launch_bounds__(BLOCK) void partial_kernel(
    const float* __restrict__ in, float* __restrict__ ws) {
  const int blk = blockIdx.x;             // 0..1279
  const int bp = blk / CHUNKS;            // 0..159
  const int chunk = blk - bp * CHUNKS;    // 0..7
  const int b = bp / NP;
  const int p = bp - b * NP;

  const float4* __restrict__ in4 =
      (const float4*)(in + ((size_t)(b * NPART + p) * HH +
                            (size_t)chunk * ROWS_PER_CHUNK) * WW);
  const int t = threadIdx.x;

  float s = 0.f, sx = 0.f, sy = 0.f, sx2 = 0.f, sy2 = 0.f;
  const float inv256 = 1.0f / 256.0f;  // 2/W = 2/H = 1/256

  #pragma unroll 4
  for (int j = 0; j < ITERS; ++j) {
    const int fi = j * BLOCK + t;        // float4 index within chunk
    const float4 v = in4[fi];
    const int row = fi >> 7;             // 128 float4 per row
    const int w0 = (fi & 127) << 2;      // starting column of this float4
    const float ym = (float)(chunk * ROWS_PER_CHUNK + row) * inv256 - 1.0f;
    const float xm0 = (float)w0 * inv256 - 1.0f;
    const float xm1 = xm0 + inv256;
    const float xm2 = xm0 + 2.0f * inv256;
    const float xm3 = xm0 + 3.0f * inv256;

    const float sum4 = (v.x + v.y) + (v.z + v.w);
    s += sum4;
    sy = fmaf(ym, sum4, sy);
    sy2 = fmaf(ym * ym, sum4, sy2);
    sx = fmaf(v.x, xm0, sx);
    sx = fmaf(v.y, xm1, sx);
    sx = fmaf(v.z, xm2, sx);
    sx = fmaf(v.w, xm3, sx);
    sx2 = fmaf(v.x, xm0 * xm0, sx2);
    sx2 = fmaf(v.y, xm1 * xm1, sx2);
    sx2 = fmaf(v.z, xm2 * xm2, sx2);
    sx2 = fmaf(v.w, xm3 * xm3, sx2);
  }

  // wave (64-lane) butterfly reduce for all 5 accumulators
  #pragma unroll
  for (int off = 32; off > 0; off >>= 1) {
    s   += __shfl_xor(s, off);
    sx  += __shfl_xor(sx, off);
    sy  += __shfl_xor(sy, off);
    sx2 += __shfl_xor(sx2, off);
    sy2 += __shfl_xor(sy2, off);
  }

  __shared__ float red[BLOCK / 64][5];
  const int wave = t >> 6;
  const int lane = t & 63;
  if (lane == 0) {
    red[wave][0] = s;
    red[wave][1] = sx;
    red[wave][2] = sy;
    red[wave][3] = sx2;
    red[wave][4] = sy2;
  }
  __syncthreads();
  if (t < 5) {
    float acc = red[0][t] + red[1][t] + red[2][t] + red[3][t];
    ws[(size_t)blk * 5 + t] = acc;
  }
}

// Stage 2: fold chunk partials per channel, apply centroid-variance algebra,
// reduce 160 contributions, write loss / B.
__global__ __launch_bounds__(BLOCK) void finalize_kernel(
    const float* __restrict__ ws, float* __restrict__ out) {
  const int t = threadIdx.x;
  float c = 0.f;
  if (t < NBP) {
    float S = 0.f, Sx = 0.f, Sy = 0.f, Sx2 = 0.f, Sy2 = 0.f;
    #pragma unroll
    for (int ch = 0; ch < CHUNKS; ++ch) {
      const float* q = ws + (size_t)(t * CHUNKS + ch) * 5;
      S   += q[0];
      Sx  += q[1];
      Sy  += q[2];
      Sx2 += q[3];
      Sy2 += q[4];
    }
    const float k = S + 1e-8f;
    const float inv = 1.0f / k;
    const float xc = Sx * inv;
    const float yc = Sy * inv;
    const float vx = (Sx2 - 2.0f * xc * Sx + xc * xc * S) * inv;
    const float vy = (Sy2 - 2.0f * yc * Sy + yc * yc * S) * inv;
    c = vx + vy;
  }

  #pragma unroll
  for (int off = 32; off > 0; off >>= 1) {
    c += __shfl_xor(c, off);
  }

  __shared__ float red[BLOCK / 64];
  const int wave = t >> 6;
  const int lane = t & 63;
  if (lane == 0) red[wave] = c;
  __syncthreads();
  if (t == 0) {
    float total = red[0] + red[1] + red[2] + red[3];
    out[0] = total * (1.0f / (float)NB);
  }
}

extern "C" void kernel_launch(void* const* d_in, const int* in_sizes, int n_in,
                              void* d_out, int out_size, void* d_ws, size_t ws_size,
                              hipStream_t stream) {
  const float* in = (const float*)d_in[0];
  float* out = (float*)d_out;
  float* ws = (float*)d_ws;  // needs NBP*CHUNKS*5*4 = 25,600 B

  partial_kernel<<<NBP * CHUNKS, BLOCK, 0, stream>>>(in, ws);
  finalize_kernel<<<1, BLOCK, 0, stream>>>(ws, out);
}

// Round 2
// 246.361 us; speedup vs baseline: 1.0061x; 1.0061x over previous
//
#include <hip/hip_runtime.h>

#define HH 512
#define WW 512
#define NPART 11
#define NP 10            // parts actually used (drop last)
#define NB 16
#define NBP (NB * NP)    // 160 channels
#define CHUNKS 16
#define ROWS_PER_CHUNK (HH / CHUNKS)           // 32
#define BLOCK 256
#define F4_PER_CHUNK (ROWS_PER_CHUNK * WW / 4) // 4096 float4 per chunk
#define ITERS (F4_PER_CHUNK / (BLOCK * 2))     // 8 iterations, 2 float4 each

// Stage 1: per (channel, chunk) block computes 5 weighted partial sums.
// ws layout: ws[(bp*CHUNKS + chunk)*5 + {S,Sx,Sy,Sx2,Sy2}]
__global__ __launch_bounds__(BLOCK) void partial_kernel(
    const float* __restrict__ in, float* __restrict__ ws) {
  const int blk = blockIdx.x;             // 0..2559
  const int bp = blk / CHUNKS;            // 0..159
  const int chunk = blk - bp * CHUNKS;    // 0..15
  const int b = bp / NP;
  const int p = bp - b * NP;

  const float4* __restrict__ in4 =
      (const float4*)(in + ((size_t)(b * NPART + p) * HH +
                            (size_t)chunk * ROWS_PER_CHUNK) * WW);
  const int t = threadIdx.x;
  const float inv256 = 1.0f / 256.0f;  // 2/W = 2/H = 1/256

  // Column map is loop-invariant per thread: fi & 127 == t & 127
  const int w0 = (t & 127) << 2;
  const float xm0 = (float)w0 * inv256 - 1.0f;
  const float xm1 = xm0 + inv256;
  const float xm2 = xm0 + 2.0f * inv256;
  const float xm3 = xm0 + 3.0f * inv256;
  const float xq0 = xm0 * xm0, xq1 = xm1 * xm1, xq2 = xm2 * xm2, xq3 = xm3 * xm3;

  float s = 0.f, sx = 0.f, sy = 0.f, sx2 = 0.f, sy2 = 0.f;

  #pragma unroll
  for (int j = 0; j < ITERS; ++j) {
    const int fi0 = (j * 2) * BLOCK + t;       // two float4 slots per iter
    const int fi1 = fi0 + BLOCK;
    const float4 v0 = in4[fi0];
    const float4 v1 = in4[fi1];

    const int row0 = fi0 >> 7;                 // 128 float4 per row
    const int row1 = fi1 >> 7;
    const float ym0 = (float)(chunk * ROWS_PER_CHUNK + row0) * inv256 - 1.0f;
    const float ym1 = (float)(chunk * ROWS_PER_CHUNK + row1) * inv256 - 1.0f;

    const float sum0 = (v0.x + v0.y) + (v0.z + v0.w);
    const float sum1 = (v1.x + v1.y) + (v1.z + v1.w);
    s += sum0 + sum1;
    sy = fmaf(ym0, sum0, sy);
    sy = fmaf(ym1, sum1, sy);
    sy2 = fmaf(ym0 * ym0, sum0, sy2);
    sy2 = fmaf(ym1 * ym1, sum1, sy2);

    sx = fmaf(v0.x, xm0, sx);  sx = fmaf(v0.y, xm1, sx);
    sx = fmaf(v0.z, xm2, sx);  sx = fmaf(v0.w, xm3, sx);
    sx = fmaf(v1.x, xm0, sx);  sx = fmaf(v1.y, xm1, sx);
    sx = fmaf(v1.z, xm2, sx);  sx = fmaf(v1.w, xm3, sx);

    sx2 = fmaf(v0.x, xq0, sx2);  sx2 = fmaf(v0.y, xq1, sx2);
    sx2 = fmaf(v0.z, xq2, sx2);  sx2 = fmaf(v0.w, xq3, sx2);
    sx2 = fmaf(v1.x, xq0, sx2);  sx2 = fmaf(v1.y, xq1, sx2);
    sx2 = fmaf(v1.z, xq2, sx2);  sx2 = fmaf(v1.w, xq3, sx2);
  }

  // wave (64-lane) butterfly reduce for all 5 accumulators
  #pragma unroll
  for (int off = 32; off > 0; off >>= 1) {
    s   += __shfl_xor(s, off);
    sx  += __shfl_xor(sx, off);
    sy  += __shfl_xor(sy, off);
    sx2 += __shfl_xor(sx2, off);
    sy2 += __shfl_xor(sy2, off);
  }

  __shared__ float red[BLOCK / 64][5];
  const int wave = t >> 6;
  const int lane = t & 63;
  if (lane == 0) {
    red[wave][0] = s;
    red[wave][1] = sx;
    red[wave][2] = sy;
    red[wave][3] = sx2;
    red[wave][4] = sy2;
  }
  __syncthreads();
  if (t < 5) {
    float acc = red[0][t] + red[1][t] + red[2][t] + red[3][t];
    ws[(size_t)blk * 5 + t] = acc;
  }
}

// Stage 2: fold chunk partials per channel, apply centroid-variance algebra,
// reduce 160 contributions, write loss / B.
__global__ __launch_bounds__(BLOCK) void finalize_kernel(
    const float* __restrict__ ws, float* __restrict__ out) {
  const int t = threadIdx.x;
  float c = 0.f;
  if (t < NBP) {
    float S = 0.f, Sx = 0.f, Sy = 0.f, Sx2 = 0.f, Sy2 = 0.f;
    #pragma unroll
    for (int ch = 0; ch < CHUNKS; ++ch) {
      const float* q = ws + (size_t)(t * CHUNKS + ch) * 5;
      S   += q[0];
      Sx  += q[1];
      Sy  += q[2];
      Sx2 += q[3];
      Sy2 += q[4];
    }
    const float k = S + 1e-8f;
    const float inv = 1.0f / k;
    const float xc = Sx * inv;
    const float yc = Sy * inv;
    const float vx = (Sx2 - 2.0f * xc * Sx + xc * xc * S) * inv;
    const float vy = (Sy2 - 2.0f * yc * Sy + yc * yc * S) * inv;
    c = vx + vy;
  }

  #pragma unroll
  for (int off = 32; off > 0; off >>= 1) {
    c += __shfl_xor(c, off);
  }

  __shared__ float red[BLOCK / 64];
  const int wave = t >> 6;
  const int lane = t & 63;
  if (lane == 0) red[wave] = c;
  __syncthreads();
  if (t == 0) {
    float total = red[0] + red[1] + red[2] + red[3];
    out[0] = total * (1.0f / (float)NB);
  }
}

extern "C" void kernel_launch(void* const* d_in, const int* in_sizes, int n_in,
                              void* d_out, int out_size, void* d_ws, size_t ws_size,
                              hipStream_t stream) {
  const float* in = (const float*)d_in[0];
  float* out = (float*)d_out;
  float* ws = (float*)d_ws;  // needs NBP*CHUNKS*5*4 = 51,200 B

  partial_kernel<<<NBP * CHUNKS, BLOCK, 0, stream>>>(in, ws);
  finalize_kernel<<<1, BLOCK, 0, stream>>>(ws, out);
}